// Round 5
// baseline (451.321 us; speedup 1.0000x reference)
//
#include <hip/hip_runtime.h>
#include <hip/hip_bf16.h>
#include <cstdint>
#include <cmath>

#define NB 4
#define NW 2048
#define DM 1024
#define NH 16
#define DK 64

typedef __attribute__((ext_vector_type(8))) short bf16x8;
typedef __attribute__((ext_vector_type(4))) float f32x4;
union cvt8 { uint4 u; __hip_bfloat16 h[8]; };
union pk2 { unsigned u; unsigned short s[2]; };

__device__ __forceinline__ void async_ld16(const void* g, void* l) {
  __builtin_amdgcn_global_load_lds((__attribute__((address_space(1))) void*)g,
                                   (__attribute__((address_space(3))) void*)l,
                                   16, 0, 0);
}

__device__ __forceinline__ unsigned short bf16bits(float x) {
  __hip_bfloat16 h = __float2bfloat16(x);
  return *(unsigned short*)&h;
}

__device__ __forceinline__ float exp2_fast(float x) {
  float r;
  asm("v_exp_f32 %0, %1" : "=v"(r) : "v"(x));
  return r;
}

// ---------------- fused fp32->bf16 converts ----------------
__global__ void __launch_bounds__(256) cvt_qkv(const float* __restrict__ Q,
                                               const float* __restrict__ K,
                                               const float* __restrict__ V,
                                               __hip_bfloat16* __restrict__ Qb,
                                               __hip_bfloat16* __restrict__ Kb,
                                               __hip_bfloat16* __restrict__ Vb) {
  const float* in = blockIdx.y == 0 ? Q : (blockIdx.y == 1 ? K : V);
  __hip_bfloat16* out = blockIdx.y == 0 ? Qb : (blockIdx.y == 1 ? Kb : Vb);
  size_t i = ((size_t)blockIdx.x * 256 + threadIdx.x) * 8;
  float4 a = *(const float4*)(in + i);
  float4 b = *(const float4*)(in + i + 4);
  cvt8 c;
#pragma unroll
  for (int t = 0; t < 4; ++t) {
    c.h[t]     = __float2bfloat16(((const float*)&a)[t]);
    c.h[4 + t] = __float2bfloat16(((const float*)&b)[t]);
  }
  *(uint4*)(out + i) = c.u;
}

__global__ void __launch_bounds__(256) cvt_w(const float* __restrict__ W0,
                                             const float* __restrict__ W1,
                                             const float* __restrict__ W2,
                                             const float* __restrict__ W3,
                                             __hip_bfloat16* __restrict__ Wb) {
  const float* in = blockIdx.y == 0 ? W0 : (blockIdx.y == 1 ? W1 : (blockIdx.y == 2 ? W2 : W3));
  __hip_bfloat16* out = Wb + (size_t)blockIdx.y * DM * DM;
  size_t i = ((size_t)blockIdx.x * 256 + threadIdx.x) * 8;
  float4 a = *(const float4*)(in + i);
  float4 b = *(const float4*)(in + i + 4);
  cvt8 c;
#pragma unroll
  for (int t = 0; t < 4; ++t) {
    c.h[t]     = __float2bfloat16(((const float*)&a)[t]);
    c.h[4 + t] = __float2bfloat16(((const float*)&b)[t]);
  }
  *(uint4*)(out + i) = c.u;
}

// ---------------- mask bitpack, TRANSPOSED output: bits[b][kt][row] ----------------
__global__ void __launch_bounds__(256) mask_pack(const int* __restrict__ mask,
                                                 unsigned long long* __restrict__ bits) {
  int lane = threadIdx.x & 63;
  size_t tid = (size_t)blockIdx.x * blockDim.x + threadIdx.x;
  size_t widx = tid >> 6;  // row-major word idx = (b*NW+row)*(NW/64) + kt
  int m = mask[widx * 64 + lane];
  unsigned long long bm = __ballot(m != 0);
  if (lane == 0) {
    int kt  = (int)(widx & 31);
    int row = (int)((widx >> 5) & 2047);
    int bb  = (int)(widx >> 16);
    bits[((size_t)bb * 32 + kt) * NW + row] = bm;
  }
}

// ---------------- fused QKV projection: y = x @ W^T (m97 structure) ----------------
// z=0: Q@Wq*(0.125*log2e) -> q_ws row-major (log2e folded so attn uses raw v_exp_f32);
// z=1: K@Wk -> k_ws row-major; z=2: V@Wv -> vt transposed [(b*16+h)*64+dim][token]
__global__ void __launch_bounds__(256) gemm_qkv(const __hip_bfloat16* __restrict__ Qb,
                                                const __hip_bfloat16* __restrict__ Kb,
                                                const __hip_bfloat16* __restrict__ Vb,
                                                const __hip_bfloat16* __restrict__ Wb,
                                                __hip_bfloat16* __restrict__ q_ws,
                                                __hip_bfloat16* __restrict__ k_ws,
                                                __hip_bfloat16* __restrict__ vt) {
  __shared__ __align__(16) __hip_bfloat16 sA[128 * 32];
  __shared__ __align__(16) __hip_bfloat16 sB[128 * 32];
  const int z = blockIdx.z;
  const __hip_bfloat16* A = z == 0 ? Qb : (z == 1 ? Kb : Vb);
  const __hip_bfloat16* W = Wb + (size_t)z * DM * DM;
  const int tid = threadIdx.x;
  const int lane = tid & 63;
  const int l15 = lane & 15, quad = lane >> 4;
  const int rowA = blockIdx.y * 128;
  const int colB = blockIdx.x * 128;
  const int wm = ((tid >> 6) >> 1) * 64, wn = ((tid >> 6) & 1) * 64;

  const f32x4 fz = {0.f, 0.f, 0.f, 0.f};
  f32x4 acc[4][4];
#pragma unroll
  for (int i = 0; i < 4; ++i)
#pragma unroll
    for (int j = 0; j < 4; ++j) acc[i][j] = fz;

  for (int k0 = 0; k0 < DM; k0 += 32) {
#pragma unroll
    for (int j = 0; j < 2; ++j) {
      int c = j * 256 + tid;
      int r = c >> 2, col = (c & 3) * 8;
      int ldsOff = (j * 256 + (tid & ~63)) * 16;
      async_ld16(A + (size_t)(rowA + r) * DM + k0 + col, (char*)sA + ldsOff);
      async_ld16(W + (size_t)(colB + r) * DM + k0 + col, (char*)sB + ldsOff);
    }
    __syncthreads();
    bf16x8 af[4], bfr[4];
#pragma unroll
    for (int i = 0; i < 4; ++i) {
      af[i]  = *(const bf16x8*)(sA + (wm + i * 16 + l15) * 32 + quad * 8);
      bfr[i] = *(const bf16x8*)(sB + (wn + i * 16 + l15) * 32 + quad * 8);
    }
#pragma unroll
    for (int i = 0; i < 4; ++i)
#pragma unroll
      for (int j = 0; j < 4; ++j)
        acc[i][j] = __builtin_amdgcn_mfma_f32_16x16x32_bf16(af[i], bfr[j], acc[i][j], 0, 0, 0);
    __syncthreads();
  }

  if (z < 2) {
    __hip_bfloat16* C = z == 0 ? q_ws : k_ws;
    // 1/sqrt(64) * log2(e) folded into q so attn softmax uses exp2 directly
    float alpha = z == 0 ? 0.18033688011112042f : 1.0f;
#pragma unroll
    for (int i = 0; i < 4; ++i) {
      int row = rowA + wm + i * 16 + quad * 4;
#pragma unroll
      for (int j = 0; j < 4; ++j) {
        int col = colB + wn + j * 16 + l15;
#pragma unroll
        for (int r = 0; r < 4; ++r)
          C[(size_t)(row + r) * DM + col] = __float2bfloat16(acc[i][j][r] * alpha);
      }
    }
  } else {
    // transposed V epilogue: vt[(b*1024 + col)][token], 4 consecutive tokens packed b64
#pragma unroll
    for (int i = 0; i < 4; ++i) {
      int row = rowA + wm + i * 16 + quad * 4;     // global token row (0..8191)
      int bb = row >> 11, tok = row & 2047;
#pragma unroll
      for (int j = 0; j < 4; ++j) {
        int col = colB + wn + j * 16 + l15;        // dim 0..1023
        uint2 u;
        u.x = (unsigned int)bf16bits(acc[i][j][0]) | ((unsigned int)bf16bits(acc[i][j][1]) << 16);
        u.y = (unsigned int)bf16bits(acc[i][j][2]) | ((unsigned int)bf16bits(acc[i][j][3]) << 16);
        *(uint2*)(vt + ((size_t)bb * 1024 + col) * 2048 + tok) = u;
      }
    }
  }
}

// ---------------- final projection: bf16 A,W -> fp32 out ----------------
__global__ void __launch_bounds__(256) gemm_out(const __hip_bfloat16* __restrict__ A,
                                                const __hip_bfloat16* __restrict__ W,
                                                float* __restrict__ C) {
  __shared__ __align__(16) __hip_bfloat16 sA[128 * 32];
  __shared__ __align__(16) __hip_bfloat16 sB[128 * 32];
  const int tid = threadIdx.x;
  const int lane = tid & 63;
  const int l15 = lane & 15, quad = lane >> 4;
  const int rowA = blockIdx.y * 128;
  const int colB = blockIdx.x * 128;
  const int wm = ((tid >> 6) >> 1) * 64, wn = ((tid >> 6) & 1) * 64;

  const f32x4 fz = {0.f, 0.f, 0.f, 0.f};
  f32x4 acc[4][4];
#pragma unroll
  for (int i = 0; i < 4; ++i)
#pragma unroll
    for (int j = 0; j < 4; ++j) acc[i][j] = fz;

  for (int k0 = 0; k0 < DM; k0 += 32) {
#pragma unroll
    for (int j = 0; j < 2; ++j) {
      int c = j * 256 + tid;
      int r = c >> 2, col = (c & 3) * 8;
      int ldsOff = (j * 256 + (tid & ~63)) * 16;
      async_ld16(A + (size_t)(rowA + r) * DM + k0 + col, (char*)sA + ldsOff);
      async_ld16(W + (size_t)(colB + r) * DM + k0 + col, (char*)sB + ldsOff);
    }
    __syncthreads();
    bf16x8 af[4], bfr[4];
#pragma unroll
    for (int i = 0; i < 4; ++i) {
      af[i]  = *(const bf16x8*)(sA + (wm + i * 16 + l15) * 32 + quad * 8);
      bfr[i] = *(const bf16x8*)(sB + (wn + i * 16 + l15) * 32 + quad * 8);
    }
#pragma unroll
    for (int i = 0; i < 4; ++i)
#pragma unroll
      for (int j = 0; j < 4; ++j)
        acc[i][j] = __builtin_amdgcn_mfma_f32_16x16x32_bf16(af[i], bfr[j], acc[i][j], 0, 0, 0);
    __syncthreads();
  }
#pragma unroll
  for (int i = 0; i < 4; ++i) {
    int row = rowA + wm + i * 16 + quad * 4;
#pragma unroll
    for (int j = 0; j < 4; ++j) {
      int col = colB + wn + j * 16 + l15;
#pragma unroll
      for (int r = 0; r < 4; ++r)
        C[(size_t)(row + r) * DM + col] = acc[i][j][r];
    }
  }
}

// ---------------- fused attention: 32 q-rows/wave, double-buffered LINEAR LDS, ----
// staging via global_load_lds (no VGPR round-trip). Both-sides XOR swizzle at 16B
// granularity: linear LDS dest, global SOURCE granule ^= row&7, READ granule ^= row&7
// (involution, G21). Write conflicts eliminated (1KB contiguous per instr); read
// bank-spread identical to the old pad-72 layout. Compute body = verified round-3.
__global__ void __launch_bounds__(256) attn_fused(const __hip_bfloat16* __restrict__ q,
                                                  const __hip_bfloat16* __restrict__ kk,
                                                  const __hip_bfloat16* __restrict__ vt,
                                                  const unsigned long long* __restrict__ mbt,
                                                  __hip_bfloat16* __restrict__ o) {
  __shared__ __align__(16) __hip_bfloat16 sK[2 * 64 * 64];   // keys, linear, dbuf (16KB)
  __shared__ __align__(16) __hip_bfloat16 sVT[2 * 64 * 64];  // V^T [dim][key], linear, dbuf

  const int tid = threadIdx.x;
  const int wave = tid >> 6, lane = tid & 63;
  const int l15 = lane & 15, quad = lane >> 4;
  const int b = blockIdx.z, h = blockIdx.y;
  const int qbase = blockIdx.x * 128 + wave * 32;

  const __hip_bfloat16* qp = q + (size_t)(b * NW + qbase + l15) * DM + h * DK + quad * 8;
  bf16x8 aq0 = *(const bf16x8*)qp;
  bf16x8 aq1 = *(const bf16x8*)(qp + 32);
  bf16x8 aq2 = *(const bf16x8*)(qp + (size_t)16 * DM);
  bf16x8 aq3 = *(const bf16x8*)(qp + (size_t)16 * DM + 32);

  const __hip_bfloat16* vbase = vt + ((size_t)b * 1024 + h * DK) * 2048;  // [dim][token]
  const unsigned long long* mrow = mbt + (size_t)b * 32 * NW + qbase + l15;  // [kt][row]

  // gload_lds staging: instr i of wave w fills LDS rows w*16+i*8 .. +7 linearly
  // (lane l -> row w*16+i*8+(l>>3), granule l&7). Source granule pre-XORed with row&7:
  // sgran = (l&7) ^ (l>>3)  (row&7 == l>>3 for both instrs).
  const int sgran = (tid & 7) ^ ((tid >> 3) & 7);
  const int Rbase = wave * 16 + ((tid >> 3) & 7);            // +8 for instr i=1
  const __hip_bfloat16* kst = kk + (size_t)(b * NW + Rbase) * DM + h * DK + sgran * 8;
  const __hip_bfloat16* vst = vbase + (size_t)Rbase * 2048 + sgran * 8;
  const int ldsWoff = wave * 2048;                           // bytes: 2 instrs x 1KB

  const f32x4 fz = {0.f, 0.f, 0.f, 0.f};
  f32x4 oacc[2][4];
#pragma unroll
  for (int g = 0; g < 2; ++g)
#pragma unroll
    for (int i = 0; i < 4; ++i) oacc[g][i] = fz;
  float lsr0[4] = {0.f, 0.f, 0.f, 0.f};
  float lsr1[4] = {0.f, 0.f, 0.f, 0.f};

  // prologue: stage tile 0 -> buf0; masks for kt=0 into regs
  async_ld16(kst,                     (char*)sK + ldsWoff);
  async_ld16(kst + (size_t)8 * DM,    (char*)sK + ldsWoff + 1024);
  async_ld16(vst,                     (char*)sVT + ldsWoff);
  async_ld16(vst + (size_t)8 * 2048,  (char*)sVT + ldsWoff + 1024);
  unsigned long long mw0 = mrow[0];
  unsigned long long mw1 = mrow[16];
  __syncthreads();

  const int xg = l15 & 7;   // read-side XOR (row&7 for rows nc*16+l15)

  for (int kt = 0; kt < NW / 64; ++kt) {
    const __hip_bfloat16* bK = sK + (kt & 1) * 4096;
    const __hip_bfloat16* bV = sVT + (kt & 1) * 4096;
    const unsigned long long cmw0 = mw0, cmw1 = mw1;
    const bool notlast = (kt + 1 < NW / 64);
    if (notlast) {
      // stage tile kt+1 into the other buffer; completes during compute, drained by
      // the end-of-iteration __syncthreads (vmcnt(0) there is free by then)
      int boff = ((kt + 1) & 1) * 8192;
      const __hip_bfloat16* kn = kst + (size_t)(kt + 1) * 64 * DM;
      const __hip_bfloat16* vn = vst + (size_t)(kt + 1) * 64;
      async_ld16(kn,                    (char*)sK + boff + ldsWoff);
      async_ld16(kn + (size_t)8 * DM,   (char*)sK + boff + ldsWoff + 1024);
      async_ld16(vn,                    (char*)sVT + boff + ldsWoff);
      async_ld16(vn + (size_t)8 * 2048, (char*)sVT + boff + ldsWoff + 1024);
      mw0 = mrow[(size_t)(kt + 1) * NW];
      mw1 = mrow[(size_t)(kt + 1) * NW + 16];
    }

    unsigned long long msh0 = cmw0 >> (quad * 4);
    unsigned long long msh1 = cmw1 >> (quad * 4);
    unsigned u0[4][2], u1[4][2];
#pragma unroll
    for (int nc = 0; nc < 4; ++nc) {
      const __hip_bfloat16* kr = bK + (nc * 16 + l15) * 64;
      bf16x8 kf0 = *(const bf16x8*)(kr + (quad ^ xg) * 8);
      bf16x8 kf1 = *(const bf16x8*)(kr + ((quad ^ xg) ^ 4) * 8);
      // swapped: S^T[k][q] -> lane(quad,l15): q=l15, k=nc*16+quad*4+r
      f32x4 t0 = fz, t1 = fz;
      t0 = __builtin_amdgcn_mfma_f32_16x16x32_bf16(kf0, aq0, t0, 0, 0, 0);
      t0 = __builtin_amdgcn_mfma_f32_16x16x32_bf16(kf1, aq1, t0, 0, 0, 0);
      t1 = __builtin_amdgcn_mfma_f32_16x16x32_bf16(kf0, aq2, t1, 0, 0, 0);
      t1 = __builtin_amdgcn_mfma_f32_16x16x32_bf16(kf1, aq3, t1, 0, 0, 0);
      unsigned nib0 = (unsigned)(msh0 >> (nc * 16)) & 0xFu;
      unsigned nib1 = (unsigned)(msh1 >> (nc * 16)) & 0xFu;
      float p0[4], p1[4];
#pragma unroll
      for (int r = 0; r < 4; ++r) {
        float e0 = exp2_fast(t0[r]);                 // q pre-scaled by log2e: exp2(S)
        float e1 = exp2_fast(t1[r]);
        if (!((nib0 >> r) & 1u)) e0 = 0.f;
        if (!((nib1 >> r) & 1u)) e1 = 0.f;
        lsr0[r] += e0;
        lsr1[r] += e1;
        p0[r] = e0;
        p1[r] = e1;
      }
      pk2 w;
      w.s[0] = bf16bits(p0[0]); w.s[1] = bf16bits(p0[1]); u0[nc][0] = w.u;
      w.s[0] = bf16bits(p0[2]); w.s[1] = bf16bits(p0[3]); u0[nc][1] = w.u;
      w.s[0] = bf16bits(p1[0]); w.s[1] = bf16bits(p1[1]); u1[nc][0] = w.u;
      w.s[0] = bf16bits(p1[2]); w.s[1] = bf16bits(p1[3]); u1[nc][1] = w.u;
    }

    // redistribute into PV A-fragment layout (per q-group):
    // word i from pair (u[nc0][i], u[nc0+1][i]) via permlane32_swap + permlane16_swap
#define PERM2(x, y)                                                  \
    asm volatile("v_permlane32_swap_b32 %0, %1" : "+v"(x), "+v"(y)); \
    asm volatile("v_permlane16_swap_b32 %0, %1" : "+v"(x), "+v"(y));
    unsigned g0a0 = u0[0][0], g0a2 = u0[1][0]; PERM2(g0a0, g0a2)
    unsigned g0a1 = u0[0][1], g0a3 = u0[1][1]; PERM2(g0a1, g0a3)
    unsigned g0c0 = u0[2][0], g0c2 = u0[3][0]; PERM2(g0c0, g0c2)
    unsigned g0c1 = u0[2][1], g0c3 = u0[3][1]; PERM2(g0c1, g0c3)
    unsigned g1a0 = u1[0][0], g1a2 = u1[1][0]; PERM2(g1a0, g1a2)
    unsigned g1a1 = u1[0][1], g1a3 = u1[1][1]; PERM2(g1a1, g1a3)
    unsigned g1c0 = u1[2][0], g1c2 = u1[3][0]; PERM2(g1c0, g1c2)
    unsigned g1c1 = u1[2][1], g1c3 = u1[3][1]; PERM2(g1c1, g1c3)
#undef PERM2

    union { unsigned w[4]; bf16x8 v; } A00, A01, A10, A11;
    A00.w[0] = g0a0; A00.w[1] = g0a1; A00.w[2] = g0a2; A00.w[3] = g0a3;  // g0 keys 0..31
    A01.w[0] = g0c0; A01.w[1] = g0c1; A01.w[2] = g0c2; A01.w[3] = g0c3;  // g0 keys 32..63
    A10.w[0] = g1a0; A10.w[1] = g1a1; A10.w[2] = g1a2; A10.w[3] = g1a3;  // g1 keys 0..31
    A11.w[0] = g1c0; A11.w[1] = g1c1; A11.w[2] = g1c2; A11.w[3] = g1c3;  // g1 keys 32..63

#pragma unroll
    for (int nc = 0; nc < 4; ++nc) {
      const __hip_bfloat16* vr = bV + (nc * 16 + l15) * 64;
      bf16x8 vf0 = *(const bf16x8*)(vr + (quad ^ xg) * 8);
      bf16x8 vf1 = *(const bf16x8*)(vr + ((quad ^ xg) ^ 4) * 8);
      oacc[0][nc] = __builtin_amdgcn_mfma_f32_16x16x32_bf16(A00.v, vf0, oacc[0][nc], 0, 0, 0);
      oacc[0][nc] = __builtin_amdgcn_mfma_f32_16x16x32_bf16(A01.v, vf1, oacc[0][nc], 0, 0, 0);
      oacc[1][nc] = __builtin_amdgcn_mfma_f32_16x16x32_bf16(A10.v, vf0, oacc[1][nc], 0, 0, 0);
      oacc[1][nc] = __builtin_amdgcn_mfma_f32_16x16x32_bf16(A11.v, vf1, oacc[1][nc], 0, 0, 0);
    }

    if (notlast) __syncthreads();   // drains this iter's async stage; next buffer ready
  }

  // fp32 row totals per group (verified round-3 pattern)
  float ls0 = (lsr0[0] + lsr0[1]) + (lsr0[2] + lsr0[3]);
  ls0 += __shfl_xor(ls0, 16, 64);
  ls0 += __shfl_xor(ls0, 32, 64);
  float ls1 = (lsr1[0] + lsr1[1]) + (lsr1[2] + lsr1[3]);
  ls1 += __shfl_xor(ls1, 16, 64);
  ls1 += __shfl_xor(ls1, 32, 64);

  float inv0[4], inv1[4];
#pragma unroll
  for (int r = 0; r < 4; ++r) {
    float lv0 = __shfl(ls0, quad * 4 + r, 64);   // row total lives at lane l15 = quad*4+r
    float lv1 = __shfl(ls1, quad * 4 + r, 64);
    inv0[r] = 1.0f / fmaxf(lv0, 1e-30f);
    inv1[r] = 1.0f / fmaxf(lv1, 1e-30f);
  }
#pragma unroll
  for (int nc = 0; nc < 4; ++nc)
#pragma unroll
    for (int r = 0; r < 4; ++r) {
      o[(size_t)(b * NW + qbase + quad * 4 + r) * DM + h * DK + nc * 16 + l15] =
          __float2bfloat16(oacc[0][nc][r] * inv0[r]);
      o[(size_t)(b * NW + qbase + 16 + quad * 4 + r) * DM + h * DK + nc * 16 + l15] =
          __float2bfloat16(oacc[1][nc][r] * inv1[r]);
    }
}

extern "C" void kernel_launch(void* const* d_in, const int* in_sizes, int n_in,
                              void* d_out, int out_size, void* d_ws, size_t ws_size,
                              hipStream_t stream) {
  const float* Q  = (const float*)d_in[0];
  const float* K  = (const float*)d_in[1];
  const float* V  = (const float*)d_in[2];
  const int*   Mm = (const int*)d_in[3];
  const float* Wq = (const float*)d_in[4];
  const float* Wk = (const float*)d_in[5];
  const float* Wv = (const float*)d_in[6];
  const float* Wo = (const float*)d_in[7];
  float* out = (float*)d_out;

  char* ws = (char*)d_ws;
  const size_t tb = (size_t)NB * NW * DM * sizeof(__hip_bfloat16);  // 16.78 MB
  const size_t wb = (size_t)DM * DM * sizeof(__hip_bfloat16);       // 2.10 MB
  // ws layout (~77.5 MB): Qb | Kb | k_ws | vt | Wb[4] | mbits
  __hip_bfloat16* Qb   = (__hip_bfloat16*)(ws);            // a_ws reuses after gemm_qkv
  __hip_bfloat16* Kb   = (__hip_bfloat16*)(ws + tb);
  __hip_bfloat16* k_ws = (__hip_bfloat16*)(ws + 2 * tb);
  __hip_bfloat16* vt   = (__hip_bfloat16*)(ws + 3 * tb);
  __hip_bfloat16* Wb   = (__hip_bfloat16*)(ws + 4 * tb);   // 4 weight slots
  unsigned long long* mbits = (unsigned long long*)(ws + 4 * tb + 4 * wb);
  // d_out (33.5 MB fp32) doubles as bf16 scratch: q_ws in first half, Vb in second
  __hip_bfloat16* q_ws = (__hip_bfloat16*)d_out;
  __hip_bfloat16* Vb   = (__hip_bfloat16*)((char*)d_out + tb);
  __hip_bfloat16* a_ws = Qb;                               // Qb dead after gemm_qkv

  const int gq = (int)((size_t)NB * NW * DM / 8 / 256);    // 4096
  const int gw = (int)((size_t)DM * DM / 8 / 256);         // 512

  mask_pack<<<(size_t)NB * NW * NW / 256, 256, 0, stream>>>(Mm, mbits);
  cvt_qkv<<<dim3(gq, 3), 256, 0, stream>>>(Q, K, V, Qb, Kb, Vb);
  cvt_w<<<dim3(gw, 4), 256, 0, stream>>>(Wq, Wk, Wv, Wo, Wb);
  gemm_qkv<<<dim3(DM / 128, NB * NW / 128, 3), 256, 0, stream>>>(Qb, Kb, Vb, Wb,
                                                                 q_ws, k_ws, vt);
  attn_fused<<<dim3(NW / 128, NH, NB), 256, 0, stream>>>(q_ws, k_ws, vt, mbits, a_ws);
  gemm_out<<<dim3(DM / 128, NB * NW / 128), 256, 0, stream>>>(a_ws, Wb + 3 * (size_t)DM * DM, out);
}

// Round 8
// 432.675 us; speedup vs baseline: 1.0431x; 1.0431x over previous
//
#include <hip/hip_runtime.h>
#include <hip/hip_bf16.h>
#include <cstdint>
#include <cmath>

#define NB 4
#define NW 2048
#define DM 1024
#define NH 16
#define DK 64

typedef __attribute__((ext_vector_type(8))) short bf16x8;
typedef __attribute__((ext_vector_type(4))) float f32x4;
union cvt8 { uint4 u; __hip_bfloat16 h[8]; };
union pk2 { unsigned u; unsigned short s[2]; };

__device__ __forceinline__ void async_ld16(const void* g, void* l) {
  __builtin_amdgcn_global_load_lds((__attribute__((address_space(1))) void*)g,
                                   (__attribute__((address_space(3))) void*)l,
                                   16, 0, 0);
}

__device__ __forceinline__ unsigned short bf16bits(float x) {
  __hip_bfloat16 h = __float2bfloat16(x);
  return *(unsigned short*)&h;
}

__device__ __forceinline__ float exp2_fast(float x) {
  float r;
  asm("v_exp_f32 %0, %1" : "=v"(r) : "v"(x));
  return r;
}

// ---------------- merged prep: cvt Q/K/V (12288 blocks) + cvt W (2048) + -----------
// mask bitpack transposed (65536). Bodies verbatim from the verified kernels;
// branch is block-uniform.
__global__ void __launch_bounds__(256) prep(const float* __restrict__ Q,
                                            const float* __restrict__ K,
                                            const float* __restrict__ V,
                                            const int* __restrict__ mask,
                                            const float* __restrict__ W0,
                                            const float* __restrict__ W1,
                                            const float* __restrict__ W2,
                                            const float* __restrict__ W3,
                                            __hip_bfloat16* __restrict__ Qb,
                                            __hip_bfloat16* __restrict__ Kb,
                                            __hip_bfloat16* __restrict__ Vb,
                                            __hip_bfloat16* __restrict__ Wb,
                                            unsigned long long* __restrict__ bits) {
  int bid = blockIdx.x;
  if (bid < 12288) {                       // cvt Q/K/V: 3 x 4096 blocks
    int by = bid >> 12;                    // /4096
    int bx = bid & 4095;
    const float* in = by == 0 ? Q : (by == 1 ? K : V);
    __hip_bfloat16* out = by == 0 ? Qb : (by == 1 ? Kb : Vb);
    size_t i = ((size_t)bx * 256 + threadIdx.x) * 8;
    float4 a = *(const float4*)(in + i);
    float4 b = *(const float4*)(in + i + 4);
    cvt8 c;
#pragma unroll
    for (int t = 0; t < 4; ++t) {
      c.h[t]     = __float2bfloat16(((const float*)&a)[t]);
      c.h[4 + t] = __float2bfloat16(((const float*)&b)[t]);
    }
    *(uint4*)(out + i) = c.u;
  } else if (bid < 14336) {                // cvt W: 4 x 512 blocks
    int t0 = bid - 12288;
    int by = t0 >> 9;                      // /512
    int bx = t0 & 511;
    const float* in = by == 0 ? W0 : (by == 1 ? W1 : (by == 2 ? W2 : W3));
    __hip_bfloat16* out = Wb + (size_t)by * DM * DM;
    size_t i = ((size_t)bx * 256 + threadIdx.x) * 8;
    float4 a = *(const float4*)(in + i);
    float4 b = *(const float4*)(in + i + 4);
    cvt8 c;
#pragma unroll
    for (int t = 0; t < 4; ++t) {
      c.h[t]     = __float2bfloat16(((const float*)&a)[t]);
      c.h[4 + t] = __float2bfloat16(((const float*)&b)[t]);
    }
    *(uint4*)(out + i) = c.u;
  } else {                                 // mask bitpack: 65536 blocks
    int bx = bid - 14336;
    int lane = threadIdx.x & 63;
    size_t tid = (size_t)bx * 256 + threadIdx.x;
    size_t widx = tid >> 6;                // row-major word idx = (b*NW+row)*(NW/64)+kt
    int m = mask[widx * 64 + lane];
    unsigned long long bm = __ballot(m != 0);
    if (lane == 0) {
      int kt  = (int)(widx & 31);
      int row = (int)((widx >> 5) & 2047);
      int bb  = (int)(widx >> 16);
      bits[((size_t)bb * 32 + kt) * NW + row] = bm;
    }
  }
}

// ---------------- fused QKV projection: y = x @ W^T (m97 structure) ----------------
// XCD-chunked swizzle (T1): linear id2 = x + 8y; XCD(id2)=id2&7; remap so XCD c owns
// rowA panels [c*8, c*8+8) x all colB -> 2MB A-chunk + 2MB W both L2-resident.
// z=0: Q@Wq*(0.125*log2e) -> q_ws row-major; z=1: K@Wk -> k_ws; z=2: V@Wv -> vt^T.
__global__ void __launch_bounds__(256) gemm_qkv(const __hip_bfloat16* __restrict__ Qb,
                                                const __hip_bfloat16* __restrict__ Kb,
                                                const __hip_bfloat16* __restrict__ Vb,
                                                const __hip_bfloat16* __restrict__ Wb,
                                                __hip_bfloat16* __restrict__ q_ws,
                                                __hip_bfloat16* __restrict__ k_ws,
                                                __hip_bfloat16* __restrict__ vt) {
  __shared__ __align__(16) __hip_bfloat16 sA[128 * 32];
  __shared__ __align__(16) __hip_bfloat16 sB[128 * 32];
  const int z = blockIdx.z;
  const __hip_bfloat16* A = z == 0 ? Qb : (z == 1 ? Kb : Vb);
  const __hip_bfloat16* W = Wb + (size_t)z * DM * DM;
  const int tid = threadIdx.x;
  const int lane = tid & 63;
  const int l15 = lane & 15, quad = lane >> 4;
  const int id2 = blockIdx.x + 8 * blockIdx.y;         // [0,512)
  const int nid2 = (id2 & 7) * 64 + (id2 >> 3);        // bijective XCD-chunk remap
  const int rowA = (nid2 >> 3) * 128;
  const int colB = (nid2 & 7) * 128;
  const int wm = ((tid >> 6) >> 1) * 64, wn = ((tid >> 6) & 1) * 64;

  const f32x4 fz = {0.f, 0.f, 0.f, 0.f};
  f32x4 acc[4][4];
#pragma unroll
  for (int i = 0; i < 4; ++i)
#pragma unroll
    for (int j = 0; j < 4; ++j) acc[i][j] = fz;

  for (int k0 = 0; k0 < DM; k0 += 32) {
#pragma unroll
    for (int j = 0; j < 2; ++j) {
      int c = j * 256 + tid;
      int r = c >> 2, col = (c & 3) * 8;
      int ldsOff = (j * 256 + (tid & ~63)) * 16;
      async_ld16(A + (size_t)(rowA + r) * DM + k0 + col, (char*)sA + ldsOff);
      async_ld16(W + (size_t)(colB + r) * DM + k0 + col, (char*)sB + ldsOff);
    }
    __syncthreads();
    bf16x8 af[4], bfr[4];
#pragma unroll
    for (int i = 0; i < 4; ++i) {
      af[i]  = *(const bf16x8*)(sA + (wm + i * 16 + l15) * 32 + quad * 8);
      bfr[i] = *(const bf16x8*)(sB + (wn + i * 16 + l15) * 32 + quad * 8);
    }
#pragma unroll
    for (int i = 0; i < 4; ++i)
#pragma unroll
      for (int j = 0; j < 4; ++j)
        acc[i][j] = __builtin_amdgcn_mfma_f32_16x16x32_bf16(af[i], bfr[j], acc[i][j], 0, 0, 0);
    __syncthreads();
  }

  if (z < 2) {
    __hip_bfloat16* C = z == 0 ? q_ws : k_ws;
    // 1/sqrt(64) * log2(e) folded into q so attn softmax uses exp2 directly
    float alpha = z == 0 ? 0.18033688011112042f : 1.0f;
#pragma unroll
    for (int i = 0; i < 4; ++i) {
      int row = rowA + wm + i * 16 + quad * 4;
#pragma unroll
      for (int j = 0; j < 4; ++j) {
        int col = colB + wn + j * 16 + l15;
#pragma unroll
        for (int r = 0; r < 4; ++r)
          C[(size_t)(row + r) * DM + col] = __float2bfloat16(acc[i][j][r] * alpha);
      }
    }
  } else {
    // transposed V epilogue: vt[(b*1024 + col)][token], 4 consecutive tokens packed b64
#pragma unroll
    for (int i = 0; i < 4; ++i) {
      int row = rowA + wm + i * 16 + quad * 4;     // global token row (0..8191)
      int bb = row >> 11, tok = row & 2047;
#pragma unroll
      for (int j = 0; j < 4; ++j) {
        int col = colB + wn + j * 16 + l15;        // dim 0..1023
        uint2 u;
        u.x = (unsigned int)bf16bits(acc[i][j][0]) | ((unsigned int)bf16bits(acc[i][j][1]) << 16);
        u.y = (unsigned int)bf16bits(acc[i][j][2]) | ((unsigned int)bf16bits(acc[i][j][3]) << 16);
        *(uint2*)(vt + ((size_t)bb * 1024 + col) * 2048 + tok) = u;
      }
    }
  }
}

// ---------------- final projection: bf16 A,W -> fp32 out (same XCD swizzle) --------
__global__ void __launch_bounds__(256) gemm_out(const __hip_bfloat16* __restrict__ A,
                                                const __hip_bfloat16* __restrict__ W,
                                                float* __restrict__ C) {
  __shared__ __align__(16) __hip_bfloat16 sA[128 * 32];
  __shared__ __align__(16) __hip_bfloat16 sB[128 * 32];
  const int tid = threadIdx.x;
  const int lane = tid & 63;
  const int l15 = lane & 15, quad = lane >> 4;
  const int id2 = blockIdx.x + 8 * blockIdx.y;         // [0,512)
  const int nid2 = (id2 & 7) * 64 + (id2 >> 3);        // bijective XCD-chunk remap
  const int rowA = (nid2 >> 3) * 128;
  const int colB = (nid2 & 7) * 128;
  const int wm = ((tid >> 6) >> 1) * 64, wn = ((tid >> 6) & 1) * 64;

  const f32x4 fz = {0.f, 0.f, 0.f, 0.f};
  f32x4 acc[4][4];
#pragma unroll
  for (int i = 0; i < 4; ++i)
#pragma unroll
    for (int j = 0; j < 4; ++j) acc[i][j] = fz;

  for (int k0 = 0; k0 < DM; k0 += 32) {
#pragma unroll
    for (int j = 0; j < 2; ++j) {
      int c = j * 256 + tid;
      int r = c >> 2, col = (c & 3) * 8;
      int ldsOff = (j * 256 + (tid & ~63)) * 16;
      async_ld16(A + (size_t)(rowA + r) * DM + k0 + col, (char*)sA + ldsOff);
      async_ld16(W + (size_t)(colB + r) * DM + k0 + col, (char*)sB + ldsOff);
    }
    __syncthreads();
    bf16x8 af[4], bfr[4];
#pragma unroll
    for (int i = 0; i < 4; ++i) {
      af[i]  = *(const bf16x8*)(sA + (wm + i * 16 + l15) * 32 + quad * 8);
      bfr[i] = *(const bf16x8*)(sB + (wn + i * 16 + l15) * 32 + quad * 8);
    }
#pragma unroll
    for (int i = 0; i < 4; ++i)
#pragma unroll
      for (int j = 0; j < 4; ++j)
        acc[i][j] = __builtin_amdgcn_mfma_f32_16x16x32_bf16(af[i], bfr[j], acc[i][j], 0, 0, 0);
    __syncthreads();
  }
#pragma unroll
  for (int i = 0; i < 4; ++i) {
    int row = rowA + wm + i * 16 + quad * 4;
#pragma unroll
    for (int j = 0; j < 4; ++j) {
      int col = colB + wn + j * 16 + l15;
#pragma unroll
      for (int r = 0; r < 4; ++r)
        C[(size_t)(row + r) * DM + col] = acc[i][j][r];
    }
  }
}

// ---------------- fused attention (VERIFIED 137.9us kernel, byte-exact) ------------
// 4 waves/block, 32 q-rows/wave, double-buffered LINEAR LDS staged via
// global_load_lds with both-sides XOR swizzle (16B granule ^= row&7).
__global__ void __launch_bounds__(256) attn_fused(const __hip_bfloat16* __restrict__ q,
                                                  const __hip_bfloat16* __restrict__ kk,
                                                  const __hip_bfloat16* __restrict__ vt,
                                                  const unsigned long long* __restrict__ mbt,
                                                  __hip_bfloat16* __restrict__ o) {
  __shared__ __align__(16) __hip_bfloat16 sK[2 * 64 * 64];   // keys, linear, dbuf (16KB)
  __shared__ __align__(16) __hip_bfloat16 sVT[2 * 64 * 64];  // V^T [dim][key], linear, dbuf

  const int tid = threadIdx.x;
  const int wave = tid >> 6, lane = tid & 63;
  const int l15 = lane & 15, quad = lane >> 4;
  const int b = blockIdx.z, h = blockIdx.y;
  const int qbase = blockIdx.x * 128 + wave * 32;

  const __hip_bfloat16* qp = q + (size_t)(b * NW + qbase + l15) * DM + h * DK + quad * 8;
  bf16x8 aq0 = *(const bf16x8*)qp;
  bf16x8 aq1 = *(const bf16x8*)(qp + 32);
  bf16x8 aq2 = *(const bf16x8*)(qp + (size_t)16 * DM);
  bf16x8 aq3 = *(const bf16x8*)(qp + (size_t)16 * DM + 32);

  const __hip_bfloat16* vbase = vt + ((size_t)b * 1024 + h * DK) * 2048;  // [dim][token]
  const unsigned long long* mrow = mbt + (size_t)b * 32 * NW + qbase + l15;  // [kt][row]

  // gload_lds staging: instr i of wave w fills LDS rows w*16+i*8 .. +7 linearly
  // (lane l -> row w*16+i*8+(l>>3), granule l&7). Source granule pre-XORed with row&7:
  // sgran = (l&7) ^ (l>>3)  (row&7 == l>>3 for both instrs).
  const int sgran = (tid & 7) ^ ((tid >> 3) & 7);
  const int Rbase = wave * 16 + ((tid >> 3) & 7);            // +8 for instr i=1
  const __hip_bfloat16* kst = kk + (size_t)(b * NW + Rbase) * DM + h * DK + sgran * 8;
  const __hip_bfloat16* vst = vbase + (size_t)Rbase * 2048 + sgran * 8;
  const int ldsWoff = wave * 2048;                           // bytes: 2 instrs x 1KB

  const f32x4 fz = {0.f, 0.f, 0.f, 0.f};
  f32x4 oacc[2][4];
#pragma unroll
  for (int g = 0; g < 2; ++g)
#pragma unroll
    for (int i = 0; i < 4; ++i) oacc[g][i] = fz;
  float lsr0[4] = {0.f, 0.f, 0.f, 0.f};
  float lsr1[4] = {0.f, 0.f, 0.f, 0.f};

  // prologue: stage tile 0 -> buf0; masks for kt=0 into regs
  async_ld16(kst,                     (char*)sK + ldsWoff);
  async_ld16(kst + (size_t)8 * DM,    (char*)sK + ldsWoff + 1024);
  async_ld16(vst,                     (char*)sVT + ldsWoff);
  async_ld16(vst + (size_t)8 * 2048,  (char*)sVT + ldsWoff + 1024);
  unsigned long long mw0 = mrow[0];
  unsigned long long mw1 = mrow[16];
  __syncthreads();

  const int xg = l15 & 7;   // read-side XOR (row&7 for rows nc*16+l15)

  for (int kt = 0; kt < NW / 64; ++kt) {
    const __hip_bfloat16* bK = sK + (kt & 1) * 4096;
    const __hip_bfloat16* bV = sVT + (kt & 1) * 4096;
    const unsigned long long cmw0 = mw0, cmw1 = mw1;
    const bool notlast = (kt + 1 < NW / 64);
    if (notlast) {
      // stage tile kt+1 into the other buffer; completes during compute, drained by
      // the end-of-iteration __syncthreads (vmcnt(0) there is free by then)
      int boff = ((kt + 1) & 1) * 8192;
      const __hip_bfloat16* kn = kst + (size_t)(kt + 1) * 64 * DM;
      const __hip_bfloat16* vn = vst + (size_t)(kt + 1) * 64;
      async_ld16(kn,                    (char*)sK + boff + ldsWoff);
      async_ld16(kn + (size_t)8 * DM,   (char*)sK + boff + ldsWoff + 1024);
      async_ld16(vn,                    (char*)sVT + boff + ldsWoff);
      async_ld16(vn + (size_t)8 * 2048, (char*)sVT + boff + ldsWoff + 1024);
      mw0 = mrow[(size_t)(kt + 1) * NW];
      mw1 = mrow[(size_t)(kt + 1) * NW + 16];
    }

    unsigned long long msh0 = cmw0 >> (quad * 4);
    unsigned long long msh1 = cmw1 >> (quad * 4);
    unsigned u0[4][2], u1[4][2];
#pragma unroll
    for (int nc = 0; nc < 4; ++nc) {
      const __hip_bfloat16* kr = bK + (nc * 16 + l15) * 64;
      bf16x8 kf0 = *(const bf16x8*)(kr + (quad ^ xg) * 8);
      bf16x8 kf1 = *(const bf16x8*)(kr + ((quad ^ xg) ^ 4) * 8);
      // swapped: S^T[k][q] -> lane(quad,l15): q=l15, k=nc*16+quad*4+r
      f32x4 t0 = fz, t1 = fz;
      t0 = __builtin_amdgcn_mfma_f32_16x16x32_bf16(kf0, aq0, t0, 0, 0, 0);
      t0 = __builtin_amdgcn_mfma_f32_16x16x32_bf16(kf1, aq1, t0, 0, 0, 0);
      t1 = __builtin_amdgcn_mfma_f32_16x16x32_bf16(kf0, aq2, t1, 0, 0, 0);
      t1 = __builtin_amdgcn_mfma_f32_16x16x32_bf16(kf1, aq3, t1, 0, 0, 0);
      unsigned nib0 = (unsigned)(msh0 >> (nc * 16)) & 0xFu;
      unsigned nib1 = (unsigned)(msh1 >> (nc * 16)) & 0xFu;
      float p0[4], p1[4];
#pragma unroll
      for (int r = 0; r < 4; ++r) {
        float e0 = exp2_fast(t0[r]);                 // q pre-scaled by log2e: exp2(S)
        float e1 = exp2_fast(t1[r]);
        if (!((nib0 >> r) & 1u)) e0 = 0.f;
        if (!((nib1 >> r) & 1u)) e1 = 0.f;
        lsr0[r] += e0;
        lsr1[r] += e1;
        p0[r] = e0;
        p1[r] = e1;
      }
      pk2 w;
      w.s[0] = bf16bits(p0[0]); w.s[1] = bf16bits(p0[1]); u0[nc][0] = w.u;
      w.s[0] = bf16bits(p0[2]); w.s[1] = bf16bits(p0[3]); u0[nc][1] = w.u;
      w.s[0] = bf16bits(p1[0]); w.s[1] = bf16bits(p1[1]); u1[nc][0] = w.u;
      w.s[0] = bf16bits(p1[2]); w.s[1] = bf16bits(p1[3]); u1[nc][1] = w.u;
    }

    // redistribute into PV A-fragment layout (per q-group):
    // word i from pair (u[nc0][i], u[nc0+1][i]) via permlane32_swap + permlane16_swap
#define PERM2(x, y)                                                  \
    asm volatile("v_permlane32_swap_b32 %0, %1" : "+v"(x), "+v"(y)); \
    asm volatile("v_permlane16_swap_b32 %0, %1" : "+v"(x), "+v"(y));
    unsigned g0a0 = u0[0][0], g0a2 = u0[1][0]; PERM2(g0a0, g0a2)
    unsigned g0a1 = u0[0][1], g0a3 = u0[1][1]; PERM2(g0a1, g0a3)
    unsigned g0c0 = u0[2][0], g0c2 = u0[3][0]; PERM2(g0c0, g0c2)
    unsigned g0c1 = u0[2][1], g0c3 = u0[3][1]; PERM2(g0c1, g0c3)
    unsigned g1a0 = u1[0][0], g1a2 = u1[1][0]; PERM2(g1a0, g1a2)
    unsigned g1a1 = u1[0][1], g1a3 = u1[1][1]; PERM2(g1a1, g1a3)
    unsigned g1c0 = u1[2][0], g1c2 = u1[3][0]; PERM2(g1c0, g1c2)
    unsigned g1c1 = u1[2][1], g1c3 = u1[3][1]; PERM2(g1c1, g1c3)
#undef PERM2

    union { unsigned w[4]; bf16x8 v; } A00, A01, A10, A11;
    A00.w[0] = g0a0; A00.w[1] = g0a1; A00.w[2] = g0a2; A00.w[3] = g0a3;  // g0 keys 0..31
    A01.w[0] = g0c0; A01.w[1] = g0c1; A01.w[2] = g0c2; A01.w[3] = g0c3;  // g0 keys 32..63
    A10.w[0] = g1a0; A10.w[1] = g1a1; A10.w[2] = g1a2; A10.w[3] = g1a3;  // g1 keys 0..31
    A11.w[0] = g1c0; A11.w[1] = g1c1; A11.w[2] = g1c2; A11.w[3] = g1c3;  // g1 keys 32..63

#pragma unroll
    for (int nc = 0; nc < 4; ++nc) {
      const __hip_bfloat16* vr = bV + (nc * 16 + l15) * 64;
      bf16x8 vf0 = *(const bf16x8*)(vr + (quad ^ xg) * 8);
      bf16x8 vf1 = *(const bf16x8*)(vr + ((quad ^ xg) ^ 4) * 8);
      oacc[0][nc] = __builtin_amdgcn_mfma_f32_16x16x32_bf16(A00.v, vf0, oacc[0][nc], 0, 0, 0);
      oacc[0][nc] = __builtin_amdgcn_mfma_f32_16x16x32_bf16(A01.v, vf1, oacc[0][nc], 0, 0, 0);
      oacc[1][nc] = __builtin_amdgcn_mfma_f32_16x16x32_bf16(A10.v, vf0, oacc[1][nc], 0, 0, 0);
      oacc[1][nc] = __builtin_amdgcn_mfma_f32_16x16x32_bf16(A11.v, vf1, oacc[1][nc], 0, 0, 0);
    }

    if (notlast) __syncthreads();   // drains this iter's async stage; next buffer ready
  }

  // fp32 row totals per group (verified pattern)
  float ls0 = (lsr0[0] + lsr0[1]) + (lsr0[2] + lsr0[3]);
  ls0 += __shfl_xor(ls0, 16, 64);
  ls0 += __shfl_xor(ls0, 32, 64);
  float ls1 = (lsr1[0] + lsr1[1]) + (lsr1[2] + lsr1[3]);
  ls1 += __shfl_xor(ls1, 16, 64);
  ls1 += __shfl_xor(ls1, 32, 64);

  float inv0[4], inv1[4];
#pragma unroll
  for (int r = 0; r < 4; ++r) {
    float lv0 = __shfl(ls0, quad * 4 + r, 64);   // row total lives at lane l15 = quad*4+r
    float lv1 = __shfl(ls1, quad * 4 + r, 64);
    inv0[r] = 1.0f / fmaxf(lv0, 1e-30f);
    inv1[r] = 1.0f / fmaxf(lv1, 1e-30f);
  }
#pragma unroll
  for (int nc = 0; nc < 4; ++nc)
#pragma unroll
    for (int r = 0; r < 4; ++r) {
      o[(size_t)(b * NW + qbase + quad * 4 + r) * DM + h * DK + nc * 16 + l15] =
          __float2bfloat16(oacc[0][nc][r] * inv0[r]);
      o[(size_t)(b * NW + qbase + 16 + quad * 4 + r) * DM + h * DK + nc * 16 + l15] =
          __float2bfloat16(oacc[1][nc][r] * inv1[r]);
    }
}

extern "C" void kernel_launch(void* const* d_in, const int* in_sizes, int n_in,
                              void* d_out, int out_size, void* d_ws, size_t ws_size,
                              hipStream_t stream) {
  const float* Q  = (const float*)d_in[0];
  const float* K  = (const float*)d_in[1];
  const float* V  = (const float*)d_in[2];
  const int*   Mm = (const int*)d_in[3];
  const float* Wq = (const float*)d_in[4];
  const float* Wk = (const float*)d_in[5];
  const float* Wv = (const float*)d_in[6];
  const float* Wo = (const float*)d_in[7];
  float* out = (float*)d_out;

  char* ws = (char*)d_ws;
  const size_t tb = (size_t)NB * NW * DM * sizeof(__hip_bfloat16);  // 16.78 MB
  const size_t wb = (size_t)DM * DM * sizeof(__hip_bfloat16);       // 2.10 MB
  // ws layout (~77.5 MB): Qb | Kb | k_ws | vt | Wb[4] | mbits
  __hip_bfloat16* Qb   = (__hip_bfloat16*)(ws);            // a_ws reuses after gemm_qkv
  __hip_bfloat16* Kb   = (__hip_bfloat16*)(ws + tb);
  __hip_bfloat16* k_ws = (__hip_bfloat16*)(ws + 2 * tb);
  __hip_bfloat16* vt   = (__hip_bfloat16*)(ws + 3 * tb);
  __hip_bfloat16* Wb   = (__hip_bfloat16*)(ws + 4 * tb);   // 4 weight slots
  unsigned long long* mbits = (unsigned long long*)(ws + 4 * tb + 4 * wb);
  // d_out (33.5 MB fp32) doubles as bf16 scratch: q_ws in first half, Vb in second
  __hip_bfloat16* q_ws = (__hip_bfloat16*)d_out;
  __hip_bfloat16* Vb   = (__hip_bfloat16*)((char*)d_out + tb);
  __hip_bfloat16* a_ws = Qb;                               // Qb dead after gemm_qkv

  // prep: 12288 cvt-QKV + 2048 cvt-W + 65536 mask blocks = 79872
  prep<<<79872, 256, 0, stream>>>(Q, K, V, Mm, Wq, Wk, Wv, Wo, Qb, Kb, Vb, Wb, mbits);
  gemm_qkv<<<dim3(DM / 128, NB * NW / 128, 3), 256, 0, stream>>>(Qb, Kb, Vb, Wb,
                                                                 q_ws, k_ws, vt);
  attn_fused<<<dim3(NW / 128, NH, NB), 256, 0, stream>>>(q_ws, k_ws, vt, mbits, a_ws);
  gemm_out<<<dim3(DM / 128, NB * NW / 128), 256, 0, stream>>>(a_ws, Wb + 3 * (size_t)DM * DM, out);
}

// Round 10
// 431.555 us; speedup vs baseline: 1.0458x; 1.0026x over previous
//
#include <hip/hip_runtime.h>
#include <hip/hip_bf16.h>
#include <cstdint>
#include <cmath>

#define NB 4
#define NW 2048
#define DM 1024
#define NH 16
#define DK 64

typedef __attribute__((ext_vector_type(8))) short bf16x8;
typedef __attribute__((ext_vector_type(4))) float f32x4;
union cvt8 { uint4 u; __hip_bfloat16 h[8]; };
union pk2 { unsigned u; unsigned short s[2]; };

__device__ __forceinline__ void async_ld16(const void* g, void* l) {
  __builtin_amdgcn_global_load_lds((__attribute__((address_space(1))) void*)g,
                                   (__attribute__((address_space(3))) void*)l,
                                   16, 0, 0);
}

__device__ __forceinline__ unsigned short bf16bits(float x) {
  __hip_bfloat16 h = __float2bfloat16(x);
  return *(unsigned short*)&h;
}

__device__ __forceinline__ float exp2_fast(float x) {
  float r;
  asm("v_exp_f32 %0, %1" : "=v"(r) : "v"(x));
  return r;
}

// ---------------- merged prep: cvt Q/K/V (12288 blocks) + cvt W (2048) + -----------
// mask bitpack transposed (65536). Bodies verbatim; branch is block-uniform.
__global__ void __launch_bounds__(256) prep(const float* __restrict__ Q,
                                            const float* __restrict__ K,
                                            const float* __restrict__ V,
                                            const int* __restrict__ mask,
                                            const float* __restrict__ W0,
                                            const float* __restrict__ W1,
                                            const float* __restrict__ W2,
                                            const float* __restrict__ W3,
                                            __hip_bfloat16* __restrict__ Qb,
                                            __hip_bfloat16* __restrict__ Kb,
                                            __hip_bfloat16* __restrict__ Vb,
                                            __hip_bfloat16* __restrict__ Wb,
                                            unsigned long long* __restrict__ bits) {
  int bid = blockIdx.x;
  if (bid < 12288) {                       // cvt Q/K/V: 3 x 4096 blocks
    int by = bid >> 12;                    // /4096
    int bx = bid & 4095;
    const float* in = by == 0 ? Q : (by == 1 ? K : V);
    __hip_bfloat16* out = by == 0 ? Qb : (by == 1 ? Kb : Vb);
    size_t i = ((size_t)bx * 256 + threadIdx.x) * 8;
    float4 a = *(const float4*)(in + i);
    float4 b = *(const float4*)(in + i + 4);
    cvt8 c;
#pragma unroll
    for (int t = 0; t < 4; ++t) {
      c.h[t]     = __float2bfloat16(((const float*)&a)[t]);
      c.h[4 + t] = __float2bfloat16(((const float*)&b)[t]);
    }
    *(uint4*)(out + i) = c.u;
  } else if (bid < 14336) {                // cvt W: 4 x 512 blocks
    int t0 = bid - 12288;
    int by = t0 >> 9;                      // /512
    int bx = t0 & 511;
    const float* in = by == 0 ? W0 : (by == 1 ? W1 : (by == 2 ? W2 : W3));
    __hip_bfloat16* out = Wb + (size_t)by * DM * DM;
    size_t i = ((size_t)bx * 256 + threadIdx.x) * 8;
    float4 a = *(const float4*)(in + i);
    float4 b = *(const float4*)(in + i + 4);
    cvt8 c;
#pragma unroll
    for (int t = 0; t < 4; ++t) {
      c.h[t]     = __float2bfloat16(((const float*)&a)[t]);
      c.h[4 + t] = __float2bfloat16(((const float*)&b)[t]);
    }
    *(uint4*)(out + i) = c.u;
  } else {                                 // mask bitpack: 65536 blocks
    int bx = bid - 14336;
    int lane = threadIdx.x & 63;
    size_t tid = (size_t)bx * 256 + threadIdx.x;
    size_t widx = tid >> 6;                // row-major word idx = (b*NW+row)*(NW/64)+kt
    int m = mask[widx * 64 + lane];
    unsigned long long bm = __ballot(m != 0);
    if (lane == 0) {
      int kt  = (int)(widx & 31);
      int row = (int)((widx >> 5) & 2047);
      int bb  = (int)(widx >> 16);
      bits[((size_t)bb * 32 + kt) * NW + row] = bm;
    }
  }
}

// ---------------- fused QKV projection: y = x @ W^T (m97 structure) ----------------
// XCD-chunked swizzle (T1). z=0: Q@Wq*(0.125*log2e) -> q_ws; z=1: K@Wk -> k_ws;
// z=2: V@Wv -> vt transposed [(b*16+h)*64+dim][token]
__global__ void __launch_bounds__(256) gemm_qkv(const __hip_bfloat16* __restrict__ Qb,
                                                const __hip_bfloat16* __restrict__ Kb,
                                                const __hip_bfloat16* __restrict__ Vb,
                                                const __hip_bfloat16* __restrict__ Wb,
                                                __hip_bfloat16* __restrict__ q_ws,
                                                __hip_bfloat16* __restrict__ k_ws,
                                                __hip_bfloat16* __restrict__ vt) {
  __shared__ __align__(16) __hip_bfloat16 sA[128 * 32];
  __shared__ __align__(16) __hip_bfloat16 sB[128 * 32];
  const int z = blockIdx.z;
  const __hip_bfloat16* A = z == 0 ? Qb : (z == 1 ? Kb : Vb);
  const __hip_bfloat16* W = Wb + (size_t)z * DM * DM;
  const int tid = threadIdx.x;
  const int lane = tid & 63;
  const int l15 = lane & 15, quad = lane >> 4;
  const int id2 = blockIdx.x + 8 * blockIdx.y;         // [0,512)
  const int nid2 = (id2 & 7) * 64 + (id2 >> 3);        // bijective XCD-chunk remap
  const int rowA = (nid2 >> 3) * 128;
  const int colB = (nid2 & 7) * 128;
  const int wm = ((tid >> 6) >> 1) * 64, wn = ((tid >> 6) & 1) * 64;

  const f32x4 fz = {0.f, 0.f, 0.f, 0.f};
  f32x4 acc[4][4];
#pragma unroll
  for (int i = 0; i < 4; ++i)
#pragma unroll
    for (int j = 0; j < 4; ++j) acc[i][j] = fz;

  for (int k0 = 0; k0 < DM; k0 += 32) {
#pragma unroll
    for (int j = 0; j < 2; ++j) {
      int c = j * 256 + tid;
      int r = c >> 2, col = (c & 3) * 8;
      int ldsOff = (j * 256 + (tid & ~63)) * 16;
      async_ld16(A + (size_t)(rowA + r) * DM + k0 + col, (char*)sA + ldsOff);
      async_ld16(W + (size_t)(colB + r) * DM + k0 + col, (char*)sB + ldsOff);
    }
    __syncthreads();
    bf16x8 af[4], bfr[4];
#pragma unroll
    for (int i = 0; i < 4; ++i) {
      af[i]  = *(const bf16x8*)(sA + (wm + i * 16 + l15) * 32 + quad * 8);
      bfr[i] = *(const bf16x8*)(sB + (wn + i * 16 + l15) * 32 + quad * 8);
    }
#pragma unroll
    for (int i = 0; i < 4; ++i)
#pragma unroll
      for (int j = 0; j < 4; ++j)
        acc[i][j] = __builtin_amdgcn_mfma_f32_16x16x32_bf16(af[i], bfr[j], acc[i][j], 0, 0, 0);
    __syncthreads();
  }

  if (z < 2) {
    __hip_bfloat16* C = z == 0 ? q_ws : k_ws;
    // 1/sqrt(64) * log2(e) folded into q so attn softmax uses exp2 directly
    float alpha = z == 0 ? 0.18033688011112042f : 1.0f;
#pragma unroll
    for (int i = 0; i < 4; ++i) {
      int row = rowA + wm + i * 16 + quad * 4;
#pragma unroll
      for (int j = 0; j < 4; ++j) {
        int col = colB + wn + j * 16 + l15;
#pragma unroll
        for (int r = 0; r < 4; ++r)
          C[(size_t)(row + r) * DM + col] = __float2bfloat16(acc[i][j][r] * alpha);
      }
    }
  } else {
    // transposed V epilogue: vt[(b*1024 + col)][token], 4 consecutive tokens packed b64
#pragma unroll
    for (int i = 0; i < 4; ++i) {
      int row = rowA + wm + i * 16 + quad * 4;     // global token row (0..8191)
      int bb = row >> 11, tok = row & 2047;
#pragma unroll
      for (int j = 0; j < 4; ++j) {
        int col = colB + wn + j * 16 + l15;        // dim 0..1023
        uint2 u;
        u.x = (unsigned int)bf16bits(acc[i][j][0]) | ((unsigned int)bf16bits(acc[i][j][1]) << 16);
        u.y = (unsigned int)bf16bits(acc[i][j][2]) | ((unsigned int)bf16bits(acc[i][j][3]) << 16);
        *(uint2*)(vt + ((size_t)bb * 1024 + col) * 2048 + tok) = u;
      }
    }
  }
}

// ---------------- final projection: bf16 A,W -> fp32 out (same XCD swizzle) --------
__global__ void __launch_bounds__(256) gemm_out(const __hip_bfloat16* __restrict__ A,
                                                const __hip_bfloat16* __restrict__ W,
                                                float* __restrict__ C) {
  __shared__ __align__(16) __hip_bfloat16 sA[128 * 32];
  __shared__ __align__(16) __hip_bfloat16 sB[128 * 32];
  const int tid = threadIdx.x;
  const int lane = tid & 63;
  const int l15 = lane & 15, quad = lane >> 4;
  const int id2 = blockIdx.x + 8 * blockIdx.y;         // [0,512)
  const int nid2 = (id2 & 7) * 64 + (id2 >> 3);        // bijective XCD-chunk remap
  const int rowA = (nid2 >> 3) * 128;
  const int colB = (nid2 & 7) * 128;
  const int wm = ((tid >> 6) >> 1) * 64, wn = ((tid >> 6) & 1) * 64;

  const f32x4 fz = {0.f, 0.f, 0.f, 0.f};
  f32x4 acc[4][4];
#pragma unroll
  for (int i = 0; i < 4; ++i)
#pragma unroll
    for (int j = 0; j < 4; ++j) acc[i][j] = fz;

  for (int k0 = 0; k0 < DM; k0 += 32) {
#pragma unroll
    for (int j = 0; j < 2; ++j) {
      int c = j * 256 + tid;
      int r = c >> 2, col = (c & 3) * 8;
      int ldsOff = (j * 256 + (tid & ~63)) * 16;
      async_ld16(A + (size_t)(rowA + r) * DM + k0 + col, (char*)sA + ldsOff);
      async_ld16(W + (size_t)(colB + r) * DM + k0 + col, (char*)sB + ldsOff);
    }
    __syncthreads();
    bf16x8 af[4], bfr[4];
#pragma unroll
    for (int i = 0; i < 4; ++i) {
      af[i]  = *(const bf16x8*)(sA + (wm + i * 16 + l15) * 32 + quad * 8);
      bfr[i] = *(const bf16x8*)(sB + (wn + i * 16 + l15) * 32 + quad * 8);
    }
#pragma unroll
    for (int i = 0; i < 4; ++i)
#pragma unroll
      for (int j = 0; j < 4; ++j)
        acc[i][j] = __builtin_amdgcn_mfma_f32_16x16x32_bf16(af[i], bfr[j], acc[i][j], 0, 0, 0);
    __syncthreads();
  }
#pragma unroll
  for (int i = 0; i < 4; ++i) {
    int row = rowA + wm + i * 16 + quad * 4;
#pragma unroll
    for (int j = 0; j < 4; ++j) {
      int col = colB + wn + j * 16 + l15;
#pragma unroll
      for (int r = 0; r < 4; ++r)
        C[(size_t)(row + r) * DM + col] = acc[i][j][r];
    }
  }
}

// ---------------- fused attention (verified compute body) + T1 XCD remap ONLY ------
// Plain __launch_bounds__(256) (the (256,4) variant produced NaN in round 8 —
// codegen suspect). 1D grid 1024; nid=(wg&7)*128+(wg>>3) bijective: XCD c owns
// logical blocks [c*128,(c+1)*128) = 8 whole (b,h) groups -> per-XCD K+V working
// set 8x512KB = 4MB = one L2. Compute byte-identical to the twice-verified kernel.
__global__ void __launch_bounds__(256) attn_fused(const __hip_bfloat16* __restrict__ q,
                                                  const __hip_bfloat16* __restrict__ kk,
                                                  const __hip_bfloat16* __restrict__ vt,
                                                  const unsigned long long* __restrict__ mbt,
                                                  __hip_bfloat16* __restrict__ o) {
  __shared__ __align__(16) __hip_bfloat16 sK[2 * 64 * 64];   // keys, linear, dbuf (16KB)
  __shared__ __align__(16) __hip_bfloat16 sVT[2 * 64 * 64];  // V^T [dim][key], linear, dbuf

  const int tid = threadIdx.x;
  const int wave = tid >> 6, lane = tid & 63;
  const int l15 = lane & 15, quad = lane >> 4;
  const int wg = blockIdx.x;
  const int nid = (wg & 7) * 128 + (wg >> 3);   // bijective XCD-chunk remap
  const int qt = nid & 15;
  const int h = (nid >> 4) & 15;
  const int b = nid >> 8;
  const int qbase = qt * 128 + wave * 32;

  const __hip_bfloat16* qp = q + (size_t)(b * NW + qbase + l15) * DM + h * DK + quad * 8;
  bf16x8 aq0 = *(const bf16x8*)qp;
  bf16x8 aq1 = *(const bf16x8*)(qp + 32);
  bf16x8 aq2 = *(const bf16x8*)(qp + (size_t)16 * DM);
  bf16x8 aq3 = *(const bf16x8*)(qp + (size_t)16 * DM + 32);

  const __hip_bfloat16* vbase = vt + ((size_t)b * 1024 + h * DK) * 2048;  // [dim][token]
  const unsigned long long* mrow = mbt + (size_t)b * 32 * NW + qbase + l15;  // [kt][row]

  // gload_lds staging: instr i of wave w fills LDS rows w*16+i*8 .. +7 linearly
  // (lane l -> row w*16+i*8+(l>>3), granule l&7). Source granule pre-XORed with row&7:
  // sgran = (l&7) ^ (l>>3)  (row&7 == l>>3 for both instrs).
  const int sgran = (tid & 7) ^ ((tid >> 3) & 7);
  const int Rbase = wave * 16 + ((tid >> 3) & 7);            // +8 for instr i=1
  const __hip_bfloat16* kst = kk + (size_t)(b * NW + Rbase) * DM + h * DK + sgran * 8;
  const __hip_bfloat16* vst = vbase + (size_t)Rbase * 2048 + sgran * 8;
  const int ldsWoff = wave * 2048;                           // bytes: 2 instrs x 1KB

  const f32x4 fz = {0.f, 0.f, 0.f, 0.f};
  f32x4 oacc[2][4];
#pragma unroll
  for (int g = 0; g < 2; ++g)
#pragma unroll
    for (int i = 0; i < 4; ++i) oacc[g][i] = fz;
  float lsr0[4] = {0.f, 0.f, 0.f, 0.f};
  float lsr1[4] = {0.f, 0.f, 0.f, 0.f};

  // prologue: stage tile 0 -> buf0; masks for kt=0 into regs
  async_ld16(kst,                     (char*)sK + ldsWoff);
  async_ld16(kst + (size_t)8 * DM,    (char*)sK + ldsWoff + 1024);
  async_ld16(vst,                     (char*)sVT + ldsWoff);
  async_ld16(vst + (size_t)8 * 2048,  (char*)sVT + ldsWoff + 1024);
  unsigned long long mw0 = mrow[0];
  unsigned long long mw1 = mrow[16];
  __syncthreads();

  const int xg = l15 & 7;   // read-side XOR (row&7 for rows nc*16+l15)

  for (int kt = 0; kt < NW / 64; ++kt) {
    const __hip_bfloat16* bK = sK + (kt & 1) * 4096;
    const __hip_bfloat16* bV = sVT + (kt & 1) * 4096;
    const unsigned long long cmw0 = mw0, cmw1 = mw1;
    const bool notlast = (kt + 1 < NW / 64);
    if (notlast) {
      // stage tile kt+1 into the other buffer; completes during compute, drained by
      // the end-of-iteration __syncthreads (vmcnt(0) there is free by then)
      int boff = ((kt + 1) & 1) * 8192;
      const __hip_bfloat16* kn = kst + (size_t)(kt + 1) * 64 * DM;
      const __hip_bfloat16* vn = vst + (size_t)(kt + 1) * 64;
      async_ld16(kn,                    (char*)sK + boff + ldsWoff);
      async_ld16(kn + (size_t)8 * DM,   (char*)sK + boff + ldsWoff + 1024);
      async_ld16(vn,                    (char*)sVT + boff + ldsWoff);
      async_ld16(vn + (size_t)8 * 2048, (char*)sVT + boff + ldsWoff + 1024);
      mw0 = mrow[(size_t)(kt + 1) * NW];
      mw1 = mrow[(size_t)(kt + 1) * NW + 16];
    }

    unsigned long long msh0 = cmw0 >> (quad * 4);
    unsigned long long msh1 = cmw1 >> (quad * 4);
    unsigned u0[4][2], u1[4][2];
#pragma unroll
    for (int nc = 0; nc < 4; ++nc) {
      const __hip_bfloat16* kr = bK + (nc * 16 + l15) * 64;
      bf16x8 kf0 = *(const bf16x8*)(kr + (quad ^ xg) * 8);
      bf16x8 kf1 = *(const bf16x8*)(kr + ((quad ^ xg) ^ 4) * 8);
      // swapped: S^T[k][q] -> lane(quad,l15): q=l15, k=nc*16+quad*4+r
      f32x4 t0 = fz, t1 = fz;
      t0 = __builtin_amdgcn_mfma_f32_16x16x32_bf16(kf0, aq0, t0, 0, 0, 0);
      t0 = __builtin_amdgcn_mfma_f32_16x16x32_bf16(kf1, aq1, t0, 0, 0, 0);
      t1 = __builtin_amdgcn_mfma_f32_16x16x32_bf16(kf0, aq2, t1, 0, 0, 0);
      t1 = __builtin_amdgcn_mfma_f32_16x16x32_bf16(kf1, aq3, t1, 0, 0, 0);
      unsigned nib0 = (unsigned)(msh0 >> (nc * 16)) & 0xFu;
      unsigned nib1 = (unsigned)(msh1 >> (nc * 16)) & 0xFu;
      float p0[4], p1[4];
#pragma unroll
      for (int r = 0; r < 4; ++r) {
        float e0 = exp2_fast(t0[r]);                 // q pre-scaled by log2e: exp2(S)
        float e1 = exp2_fast(t1[r]);
        if (!((nib0 >> r) & 1u)) e0 = 0.f;
        if (!((nib1 >> r) & 1u)) e1 = 0.f;
        lsr0[r] += e0;
        lsr1[r] += e1;
        p0[r] = e0;
        p1[r] = e1;
      }
      pk2 w;
      w.s[0] = bf16bits(p0[0]); w.s[1] = bf16bits(p0[1]); u0[nc][0] = w.u;
      w.s[0] = bf16bits(p0[2]); w.s[1] = bf16bits(p0[3]); u0[nc][1] = w.u;
      w.s[0] = bf16bits(p1[0]); w.s[1] = bf16bits(p1[1]); u1[nc][0] = w.u;
      w.s[0] = bf16bits(p1[2]); w.s[1] = bf16bits(p1[3]); u1[nc][1] = w.u;
    }

    // redistribute into PV A-fragment layout (per q-group):
    // word i from pair (u[nc0][i], u[nc0+1][i]) via permlane32_swap + permlane16_swap
#define PERM2(x, y)                                                  \
    asm volatile("v_permlane32_swap_b32 %0, %1" : "+v"(x), "+v"(y)); \
    asm volatile("v_permlane16_swap_b32 %0, %1" : "+v"(x), "+v"(y));
    unsigned g0a0 = u0[0][0], g0a2 = u0[1][0]; PERM2(g0a0, g0a2)
    unsigned g0a1 = u0[0][1], g0a3 = u0[1][1]; PERM2(g0a1, g0a3)
    unsigned g0c0 = u0[2][0], g0c2 = u0[3][0]; PERM2(g0c0, g0c2)
    unsigned g0c1 = u0[2][1], g0c3 = u0[3][1]; PERM2(g0c1, g0c3)
    unsigned g1a0 = u1[0][0], g1a2 = u1[1][0]; PERM2(g1a0, g1a2)
    unsigned g1a1 = u1[0][1], g1a3 = u1[1][1]; PERM2(g1a1, g1a3)
    unsigned g1c0 = u1[2][0], g1c2 = u1[3][0]; PERM2(g1c0, g1c2)
    unsigned g1c1 = u1[2][1], g1c3 = u1[3][1]; PERM2(g1c1, g1c3)
#undef PERM2

    union { unsigned w[4]; bf16x8 v; } A00, A01, A10, A11;
    A00.w[0] = g0a0; A00.w[1] = g0a1; A00.w[2] = g0a2; A00.w[3] = g0a3;  // g0 keys 0..31
    A01.w[0] = g0c0; A01.w[1] = g0c1; A01.w[2] = g0c2; A01.w[3] = g0c3;  // g0 keys 32..63
    A10.w[0] = g1a0; A10.w[1] = g1a1; A10.w[2] = g1a2; A10.w[3] = g1a3;  // g1 keys 0..31
    A11.w[0] = g1c0; A11.w[1] = g1c1; A11.w[2] = g1c2; A11.w[3] = g1c3;  // g1 keys 32..63

#pragma unroll
    for (int nc = 0; nc < 4; ++nc) {
      const __hip_bfloat16* vr = bV + (nc * 16 + l15) * 64;
      bf16x8 vf0 = *(const bf16x8*)(vr + (quad ^ xg) * 8);
      bf16x8 vf1 = *(const bf16x8*)(vr + ((quad ^ xg) ^ 4) * 8);
      oacc[0][nc] = __builtin_amdgcn_mfma_f32_16x16x32_bf16(A00.v, vf0, oacc[0][nc], 0, 0, 0);
      oacc[0][nc] = __builtin_amdgcn_mfma_f32_16x16x32_bf16(A01.v, vf1, oacc[0][nc], 0, 0, 0);
      oacc[1][nc] = __builtin_amdgcn_mfma_f32_16x16x32_bf16(A10.v, vf0, oacc[1][nc], 0, 0, 0);
      oacc[1][nc] = __builtin_amdgcn_mfma_f32_16x16x32_bf16(A11.v, vf1, oacc[1][nc], 0, 0, 0);
    }

    if (notlast) __syncthreads();   // drains this iter's async stage; next buffer ready
  }

  // fp32 row totals per group (verified pattern)
  float ls0 = (lsr0[0] + lsr0[1]) + (lsr0[2] + lsr0[3]);
  ls0 += __shfl_xor(ls0, 16, 64);
  ls0 += __shfl_xor(ls0, 32, 64);
  float ls1 = (lsr1[0] + lsr1[1]) + (lsr1[2] + lsr1[3]);
  ls1 += __shfl_xor(ls1, 16, 64);
  ls1 += __shfl_xor(ls1, 32, 64);

  float inv0[4], inv1[4];
#pragma unroll
  for (int r = 0; r < 4; ++r) {
    float lv0 = __shfl(ls0, quad * 4 + r, 64);   // row total lives at lane l15 = quad*4+r
    float lv1 = __shfl(ls1, quad * 4 + r, 64);
    inv0[r] = 1.0f / fmaxf(lv0, 1e-30f);
    inv1[r] = 1.0f / fmaxf(lv1, 1e-30f);
  }
#pragma unroll
  for (int nc = 0; nc < 4; ++nc)
#pragma unroll
    for (int r = 0; r < 4; ++r) {
      o[(size_t)(b * NW + qbase + quad * 4 + r) * DM + h * DK + nc * 16 + l15] =
          __float2bfloat16(oacc[0][nc][r] * inv0[r]);
      o[(size_t)(b * NW + qbase + 16 + quad * 4 + r) * DM + h * DK + nc * 16 + l15] =
          __float2bfloat16(oacc[1][nc][r] * inv1[r]);
    }
}

extern "C" void kernel_launch(void* const* d_in, const int* in_sizes, int n_in,
                              void* d_out, int out_size, void* d_ws, size_t ws_size,
                              hipStream_t stream) {
  const float* Q  = (const float*)d_in[0];
  const float* K  = (const float*)d_in[1];
  const float* V  = (const float*)d_in[2];
  const int*   Mm = (const int*)d_in[3];
  const float* Wq = (const float*)d_in[4];
  const float* Wk = (const float*)d_in[5];
  const float* Wv = (const float*)d_in[6];
  const float* Wo = (const float*)d_in[7];
  float* out = (float*)d_out;

  char* ws = (char*)d_ws;
  const size_t tb = (size_t)NB * NW * DM * sizeof(__hip_bfloat16);  // 16.78 MB
  const size_t wb = (size_t)DM * DM * sizeof(__hip_bfloat16);       // 2.10 MB
  // ws layout (~77.5 MB): Qb | Kb | k_ws | vt | Wb[4] | mbits
  __hip_bfloat16* Qb   = (__hip_bfloat16*)(ws);            // a_ws reuses after gemm_qkv
  __hip_bfloat16* Kb   = (__hip_bfloat16*)(ws + tb);
  __hip_bfloat16* k_ws = (__hip_bfloat16*)(ws + 2 * tb);
  __hip_bfloat16* vt   = (__hip_bfloat16*)(ws + 3 * tb);
  __hip_bfloat16* Wb   = (__hip_bfloat16*)(ws + 4 * tb);   // 4 weight slots
  unsigned long long* mbits = (unsigned long long*)(ws + 4 * tb + 4 * wb);
  // d_out (33.5 MB fp32) doubles as bf16 scratch: q_ws in first half, Vb in second
  __hip_bfloat16* q_ws = (__hip_bfloat16*)d_out;
  __hip_bfloat16* Vb   = (__hip_bfloat16*)((char*)d_out + tb);
  __hip_bfloat16* a_ws = Qb;                               // Qb dead after gemm_qkv

  // prep: 12288 cvt-QKV + 2048 cvt-W + 65536 mask blocks = 79872
  prep<<<79872, 256, 0, stream>>>(Q, K, V, Mm, Wq, Wk, Wv, Wo, Qb, Kb, Vb, Wb, mbits);
  gemm_qkv<<<dim3(DM / 128, NB * NW / 128, 3), 256, 0, stream>>>(Qb, Kb, Vb, Wb,
                                                                 q_ws, k_ws, vt);
  attn_fused<<<dim3(1024), 256, 0, stream>>>(q_ws, k_ws, vt, mbits, a_ws);
  gemm_out<<<dim3(DM / 128, NB * NW / 128), 256, 0, stream>>>(a_ws, Wb + 3 * (size_t)DM * DM, out);
}